// Round 11
// baseline (136.074 us; speedup 1.0000x reference)
//
#include <hip/hip_runtime.h>
#include <hip/hip_bf16.h>

#define HH 96
#define WW 96
#define HW 9216
#define NB 8

typedef __bf16 bf16x8 __attribute__((ext_vector_type(8)));
typedef float  f32x4  __attribute__((ext_vector_type(4)));

union BF8 { uint4 u; bf16x8 v; unsigned short s[8]; };

__device__ __forceinline__ unsigned short f2bf_bits(float f) {
    unsigned u = __float_as_uint(f);
    unsigned r = u + 0x7FFFu + ((u >> 16) & 1u);     // RNE
    return (unsigned short)(r >> 16);
}
__device__ __forceinline__ float bf2f(unsigned short s) {
    return __uint_as_float(((unsigned)s) << 16);
}
__device__ __forceinline__ unsigned pkbf(float a, float b) {   // v_cvt_pk_bf16_f32
    union { __hip_bfloat162 h; unsigned u; } c;
    c.h = __float22bfloat162_rn(make_float2(a, b));
    return c.u;
}

// bilinear setup: 4 clamped corner base offsets (in shorts) + 4 mask-folded weights
__device__ __forceinline__ void bl_setup(int h, int w, int r, int s, float oy, float ox,
                                         int* a, float* wg) {
    float sy = (float)(h + r) + oy;
    float sx = (float)(w + s) + ox;
    float fy = floorf(sy), fx = floorf(sx);
    int   y0 = (int)fy, x0 = (int)fx;
    int   y1 = y0 + 1, x1 = x0 + 1;
    float wy1 = sy - fy, wx1 = sx - fx;
    float wy0 = 1.f - wy1, wx0 = 1.f - wx1;
    float m00 = (y0 >= 0 && y0 < HH && x0 >= 0 && x0 < WW) ? 1.f : 0.f;
    float m01 = (y0 >= 0 && y0 < HH && x1 >= 0 && x1 < WW) ? 1.f : 0.f;
    float m10 = (y1 >= 0 && y1 < HH && x0 >= 0 && x0 < WW) ? 1.f : 0.f;
    float m11 = (y1 >= 0 && y1 < HH && x1 >= 0 && x1 < WW) ? 1.f : 0.f;
    int cy0 = min(max(y0, 0), HH - 1), cy1 = min(max(y1, 0), HH - 1);
    int cx0 = min(max(x0, 0), WW - 1), cx1 = min(max(x1, 0), WW - 1);
    a[0] = (cy0 * WW + cx0) * 64;  a[1] = (cy0 * WW + cx1) * 64;
    a[2] = (cy1 * WW + cx0) * 64;  a[3] = (cy1 * WW + cx1) * 64;
    wg[0] = wy0 * wx0 * m00;  wg[1] = wy0 * wx1 * m01;
    wg[2] = wy1 * wx0 * m10;  wg[3] = wy1 * wx1 * m11;
}

// ---------------------------------------------------------------------------
// Kernel 1: x NCHW fp32 -> xt NHWC bf16 (LDS transpose, XOR-swizzled).
// Blocks < 216 also build wTb [tap][co][c] and owTb [j(32)][tap*64+c].
// (unchanged — near BW floor)
// ---------------------------------------------------------------------------
__global__ __launch_bounds__(256) void xcvt_prep(const float* __restrict__ x,
                                                 const float* __restrict__ weight,
                                                 const float* __restrict__ off_w,
                                                 unsigned short* __restrict__ xt,
                                                 unsigned short* __restrict__ wTb,
                                                 unsigned short* __restrict__ owTb) {
    __shared__ unsigned short T[64 * 64];   // [px][8 chunks], chunk' = chunk ^ (px&7)
    int bid   = blockIdx.x;                 // 1152
    int t     = threadIdx.x;
    int b     = bid & 7;                    // XCD-affine
    int pbase = (bid >> 3) * 64;
    int pl    = t & 63;
    int q     = t >> 6;                     // c-group 0..3 (chunks 2q, 2q+1)

    const float* xp = x + ((size_t)(b * 64 + q * 16)) * HW + pbase + pl;
    unsigned short hb[16];
#pragma unroll
    for (int i = 0; i < 16; ++i) hb[i] = f2bf_bits(xp[(size_t)i * HW]);

    uint4 w0, w1;
    w0.x = hb[0]  | (hb[1]  << 16); w0.y = hb[2]  | (hb[3]  << 16);
    w0.z = hb[4]  | (hb[5]  << 16); w0.w = hb[6]  | (hb[7]  << 16);
    w1.x = hb[8]  | (hb[9]  << 16); w1.y = hb[10] | (hb[11] << 16);
    w1.z = hb[12] | (hb[13] << 16); w1.w = hb[14] | (hb[15] << 16);
    int sw = pl & 7;
    *(uint4*)&T[pl * 64 + (((2 * q)     ^ sw) << 3)] = w0;
    *(uint4*)&T[pl * 64 + (((2 * q + 1) ^ sw) << 3)] = w1;
    __syncthreads();

    int row = t >> 2, rs = row & 7;
    uint4 a  = *(const uint4*)&T[row * 64 + ((((t & 3) * 2)     ^ rs) << 3)];
    uint4 b2 = *(const uint4*)&T[row * 64 + ((((t & 3) * 2 + 1) ^ rs) << 3)];
    unsigned short* dst = xt + ((size_t)(b * HW + pbase)) * 64 + t * 16;
    *(uint4*)dst       = a;
    *(uint4*)(dst + 8) = b2;

    if (bid < 216) {                        // 216*256 = 36864 + 18432
        int i = bid * 256 + t;
        if (i < 36864) {
            int tap = i >> 12;
            int co  = (i >> 6) & 63;
            int c   = i & 63;
            wTb[i] = f2bf_bits(weight[(co * 64 + c) * 9 + tap]);
        } else {
            int f   = i - 36864;
            int j   = f / 576;
            int kk  = f - j * 576;
            int tap = kk >> 6;
            int c   = kk & 63;
            owTb[f] = (j < 18) ? f2bf_bits(off_w[(j * 64 + c) * 9 + tap]) : (unsigned short)0;
        }
    }
}

// ---------------------------------------------------------------------------
// Kernel 2 (fused, 32-px tiles, 2304 blocks): 1 pixel per staging thread
// (4 corner loads/tap), register-resident offsets, double-buffered S with
// 1 barrier/tap, B-fragments direct from L1. ~9 blocks/CU for barrier overlap.
// ---------------------------------------------------------------------------
__global__ __launch_bounds__(256) void deform_all(const unsigned short* __restrict__ xt,
                                                  const unsigned short* __restrict__ wTb,
                                                  const unsigned short* __restrict__ owTb,
                                                  const float* __restrict__ bias,
                                                  const float* __restrict__ ob,
                                                  float* __restrict__ out) {
    __shared__ unsigned short S[2][32 * 64];   // [buf][px][chunk'], chunk' = chunk ^ (px&7)
    __shared__ float offs[32 * 20];            // [px][18 j + pad]

    int bid   = blockIdx.x;                 // 2304 = 8 images x 288 tiles
    int t     = threadIdx.x;
    int b     = bid & 7;                    // image per XCD
    int pbase = (bid >> 3) * 32;            // 32-px tile

    // staging role: thread = (pixel, chunk)
    int e   = t & 7;
    int pxl = t >> 3;                       // 0..31
    int px  = pbase + pxl;
    int h   = px / WW, w = px - h * WW;
    int sw  = pxl & 7;

    // MFMA roles
    int ln = t & 15;
    int qd = (t >> 4) & 3;
    int wv = t >> 6;                        // wave id

    const unsigned short* xb = xt + (size_t)b * HW * 64;

    // ================= phase A: offset conv (D = [32 px][32 j]) =================
    // wave wv: px-tile pt = wv&1, j-tile jt = wv>>1
    int ptA = wv & 1, jtA = wv >> 1;
    f32x4 accj = {0.f, 0.f, 0.f, 0.f};

    for (int tap = 0; tap < 9; ++tap) {
        int cur = tap & 1;
        int r = tap / 3, s = tap - r * 3;

        int  iy = h - 1 + r, ix = w - 1 + s;
        bool vd = (iy >= 0) & (iy < HH) & (ix >= 0) & (ix < WW);
        int  ad = (min(max(iy, 0), HH - 1) * WW + min(max(ix, 0), WW - 1)) * 64;
        uint4 p = *(const uint4*)(xb + ad + e * 8);
        if (!vd) p = make_uint4(0, 0, 0, 0);
        *(uint4*)&S[cur][pxl * 64 + ((e ^ sw) << 3)] = p;
        __syncthreads();

        int  row = ptA * 16 + ln, rs = row & 7;
        BF8  fa0, fa1, fb0, fb1;
        fa0.u = *(const uint4*)&S[cur][row * 64 + ((qd       ^ rs) << 3)];
        fa1.u = *(const uint4*)&S[cur][row * 64 + (((qd + 4) ^ rs) << 3)];
        const unsigned short* brow = owTb + (size_t)(jtA * 16 + ln) * 576 + tap * 64 + qd * 8;
        fb0.u = *(const uint4*)brow;
        fb1.u = *(const uint4*)(brow + 32);
        accj = __builtin_amdgcn_mfma_f32_16x16x32_bf16(fa0.v, fb0.v, accj, 0, 0, 0);
        accj = __builtin_amdgcn_mfma_f32_16x16x32_bf16(fa1.v, fb1.v, accj, 0, 0, 0);
        // no second barrier: next tap writes the other S buffer
    }

    // D col = j (jtA*16+ln), rows = ptA*16 + qd*4 + rg -> offs[px][j]
    {
        int j = jtA * 16 + ln;
        if (j < 18) {
            int   rowp = ptA * 16 + qd * 4;
            float obj  = ob[j];
#pragma unroll
            for (int rg = 0; rg < 4; ++rg) offs[(rowp + rg) * 20 + j] = accj[rg] + obj;
        }
    }
    __syncthreads();   // offs visible; orders phase-A S reads before phase-B writes

    // prefetch all 9 offset pairs into registers
    float oy[9], ox[9];
#pragma unroll
    for (int k = 0; k < 9; ++k) {
        float2 p = *(const float2*)&offs[pxl * 20 + 2 * k];
        oy[k] = p.x; ox[k] = p.y;
    }

    // ================= phase B: deformable conv (D = [32 px][64 co]) =================
    f32x4 acc[2] = {{0.f,0.f,0.f,0.f},{0.f,0.f,0.f,0.f}};

    for (int tap = 0; tap < 9; ++tap) {
        int cur = tap & 1;
        int r = tap / 3, s = tap - r * 3;

        int   a[4];
        float g[4];
        bl_setup(h, w, r, s, oy[tap], ox[tap], a, g);

        uint4 cA[4];
#pragma unroll
        for (int c = 0; c < 4; ++c) cA[c] = *(const uint4*)(xb + a[c] + e * 8);

        BF8 q0, q1, q2, q3;
        q0.u = cA[0]; q1.u = cA[1]; q2.u = cA[2]; q3.u = cA[3];
        float v[8];
#pragma unroll
        for (int i = 0; i < 8; ++i)
            v[i] = g[0] * bf2f(q0.s[i]) + g[1] * bf2f(q1.s[i])
                 + g[2] * bf2f(q2.s[i]) + g[3] * bf2f(q3.s[i]);
        uint4 sv;
        sv.x = pkbf(v[0], v[1]); sv.y = pkbf(v[2], v[3]);
        sv.z = pkbf(v[4], v[5]); sv.w = pkbf(v[6], v[7]);
        *(uint4*)&S[cur][pxl * 64 + ((e ^ sw) << 3)] = sv;
        __syncthreads();

        // MFMA: wave wv = co-tile, 2 px-tiles; B-frags direct from L1-hot wTb
        {
            const unsigned short* wb = wTb + (size_t)tap * 4096 + (wv * 16 + ln) * 64 + qd * 8;
            BF8 fb0, fb1;
            fb0.u = *(const uint4*)wb;
            fb1.u = *(const uint4*)(wb + 32);
#pragma unroll
            for (int pt = 0; pt < 2; ++pt) {
                int row = pt * 16 + ln, rs = row & 7;
                BF8 fa0, fa1;
                fa0.u = *(const uint4*)&S[cur][row * 64 + ((qd       ^ rs) << 3)];
                fa1.u = *(const uint4*)&S[cur][row * 64 + (((qd + 4) ^ rs) << 3)];
                acc[pt] = __builtin_amdgcn_mfma_f32_16x16x32_bf16(fa0.v, fb0.v, acc[pt], 0, 0, 0);
                acc[pt] = __builtin_amdgcn_mfma_f32_16x16x32_bf16(fa1.v, fb1.v, acc[pt], 0, 0, 0);
            }
        }
        // no second barrier (double buffer)
    }

    // ---- epilogue: D col=co, rows px = pt*16 + qd*4 + rg ----
    int   co = wv * 16 + ln;
    float bv = bias[co];
    float* ob2 = out + ((size_t)(b * 64 + co)) * HW + pbase + qd * 4;
#pragma unroll
    for (int pt = 0; pt < 2; ++pt) {
        float4 st;
        st.x = acc[pt].x + bv; st.y = acc[pt].y + bv;
        st.z = acc[pt].z + bv; st.w = acc[pt].w + bv;
        *(float4*)(ob2 + pt * 16) = st;
    }
}

// ---------------------------------------------------------------------------
extern "C" void kernel_launch(void* const* d_in, const int* in_sizes, int n_in,
                              void* d_out, int out_size, void* d_ws, size_t ws_size,
                              hipStream_t stream) {
    const float* x      = (const float*)d_in[0];   // 8*64*96*96
    const float* weight = (const float*)d_in[1];   // 64*64*3*3
    const float* bias   = (const float*)d_in[2];   // 64
    const float* off_w  = (const float*)d_in[3];   // 18*64*3*3
    const float* off_b  = (const float*)d_in[4];   // 18
    float* out = (float*)d_out;

    unsigned short* xt   = (unsigned short*)d_ws;  // 4,718,592 bf16
    unsigned short* wTb  = xt + 4718592;           // 36,864 bf16
    unsigned short* owTb = wTb + 36864;            // 18,432 bf16

    hipLaunchKernelGGL(xcvt_prep,  dim3(1152), dim3(256), 0, stream,
                       x, weight, off_w, xt, wTb, owTb);
    hipLaunchKernelGGL(deform_all, dim3(2304), dim3(256), 0, stream,
                       xt, wTb, owTb, bias, off_b, out);
}

// Round 12
// 131.203 us; speedup vs baseline: 1.0371x; 1.0371x over previous
//
#include <hip/hip_runtime.h>
#include <hip/hip_bf16.h>

#define HH 96
#define WW 96
#define HW 9216
#define NB 8

typedef __bf16 bf16x8 __attribute__((ext_vector_type(8)));
typedef float  f32x4  __attribute__((ext_vector_type(4)));

union BF8 { uint4 u; bf16x8 v; unsigned short s[8]; };

__device__ __forceinline__ unsigned short f2bf_bits(float f) {
    unsigned u = __float_as_uint(f);
    unsigned r = u + 0x7FFFu + ((u >> 16) & 1u);     // RNE
    return (unsigned short)(r >> 16);
}
__device__ __forceinline__ float bf2f(unsigned short s) {
    return __uint_as_float(((unsigned)s) << 16);
}
__device__ __forceinline__ unsigned pkbf(float a, float b) {   // v_cvt_pk_bf16_f32
    union { __hip_bfloat162 h; unsigned u; } c;
    c.h = __float22bfloat162_rn(make_float2(a, b));
    return c.u;
}

// bilinear setup: 4 clamped corner base offsets (in shorts) + 4 mask-folded weights
__device__ __forceinline__ void bl_setup(int h, int w, int r, int s, float oy, float ox,
                                         int* a, float* wg) {
    float sy = (float)(h + r) + oy;
    float sx = (float)(w + s) + ox;
    float fy = floorf(sy), fx = floorf(sx);
    int   y0 = (int)fy, x0 = (int)fx;
    int   y1 = y0 + 1, x1 = x0 + 1;
    float wy1 = sy - fy, wx1 = sx - fx;
    float wy0 = 1.f - wy1, wx0 = 1.f - wx1;
    float m00 = (y0 >= 0 && y0 < HH && x0 >= 0 && x0 < WW) ? 1.f : 0.f;
    float m01 = (y0 >= 0 && y0 < HH && x1 >= 0 && x1 < WW) ? 1.f : 0.f;
    float m10 = (y1 >= 0 && y1 < HH && x0 >= 0 && x0 < WW) ? 1.f : 0.f;
    float m11 = (y1 >= 0 && y1 < HH && x1 >= 0 && x1 < WW) ? 1.f : 0.f;
    int cy0 = min(max(y0, 0), HH - 1), cy1 = min(max(y1, 0), HH - 1);
    int cx0 = min(max(x0, 0), WW - 1), cx1 = min(max(x1, 0), WW - 1);
    a[0] = (cy0 * WW + cx0) * 64;  a[1] = (cy0 * WW + cx1) * 64;
    a[2] = (cy1 * WW + cx0) * 64;  a[3] = (cy1 * WW + cx1) * 64;
    wg[0] = wy0 * wx0 * m00;  wg[1] = wy0 * wx1 * m01;
    wg[2] = wy1 * wx0 * m10;  wg[3] = wy1 * wx1 * m11;
}

// ---------------------------------------------------------------------------
// Kernel 1: x NCHW fp32 -> xt NHWC bf16 (LDS transpose, XOR-swizzled).
// Blocks < 216 also build wTb [tap][co][c] and owTb [j(32)][tap*64+c].
// (unchanged — near BW floor)
// ---------------------------------------------------------------------------
__global__ __launch_bounds__(256) void xcvt_prep(const float* __restrict__ x,
                                                 const float* __restrict__ weight,
                                                 const float* __restrict__ off_w,
                                                 unsigned short* __restrict__ xt,
                                                 unsigned short* __restrict__ wTb,
                                                 unsigned short* __restrict__ owTb) {
    __shared__ unsigned short T[64 * 64];   // [px][8 chunks], chunk' = chunk ^ (px&7)
    int bid   = blockIdx.x;                 // 1152
    int t     = threadIdx.x;
    int b     = bid & 7;                    // XCD-affine
    int pbase = (bid >> 3) * 64;
    int pl    = t & 63;
    int q     = t >> 6;                     // c-group 0..3 (chunks 2q, 2q+1)

    const float* xp = x + ((size_t)(b * 64 + q * 16)) * HW + pbase + pl;
    unsigned short hb[16];
#pragma unroll
    for (int i = 0; i < 16; ++i) hb[i] = f2bf_bits(xp[(size_t)i * HW]);

    uint4 w0, w1;
    w0.x = hb[0]  | (hb[1]  << 16); w0.y = hb[2]  | (hb[3]  << 16);
    w0.z = hb[4]  | (hb[5]  << 16); w0.w = hb[6]  | (hb[7]  << 16);
    w1.x = hb[8]  | (hb[9]  << 16); w1.y = hb[10] | (hb[11] << 16);
    w1.z = hb[12] | (hb[13] << 16); w1.w = hb[14] | (hb[15] << 16);
    int sw = pl & 7;
    *(uint4*)&T[pl * 64 + (((2 * q)     ^ sw) << 3)] = w0;
    *(uint4*)&T[pl * 64 + (((2 * q + 1) ^ sw) << 3)] = w1;
    __syncthreads();

    int row = t >> 2, rs = row & 7;
    uint4 a  = *(const uint4*)&T[row * 64 + ((((t & 3) * 2)     ^ rs) << 3)];
    uint4 b2 = *(const uint4*)&T[row * 64 + ((((t & 3) * 2 + 1) ^ rs) << 3)];
    unsigned short* dst = xt + ((size_t)(b * HW + pbase)) * 64 + t * 16;
    *(uint4*)dst       = a;
    *(uint4*)(dst + 8) = b2;

    if (bid < 216) {                        // 216*256 = 36864 + 18432
        int i = bid * 256 + t;
        if (i < 36864) {
            int tap = i >> 12;
            int co  = (i >> 6) & 63;
            int c   = i & 63;
            wTb[i] = f2bf_bits(weight[(co * 64 + c) * 9 + tap]);
        } else {
            int f   = i - 36864;
            int j   = f / 576;
            int kk  = f - j * 576;
            int tap = kk >> 6;
            int c   = kk & 63;
            owTb[f] = (j < 18) ? f2bf_bits(off_w[(j * 64 + c) * 9 + tap]) : (unsigned short)0;
        }
    }
}

// ---------------------------------------------------------------------------
// Kernel 2 (fused): 32-px row-aligned tiles, 2304 blocks.
// Phase A: zero-padded 3x34 halo in LDS (1 load pass + 1 barrier), then all
//          9 taps' A-frags are direct swizzled ds_reads -> MFMA vs owTb (L1).
// Phase B: 2 taps per barrier (paired double-buffer, 5 barriers) with
//          cross-step register prefetch of the next pair's 8 corner loads.
// ---------------------------------------------------------------------------
__global__ __launch_bounds__(256, 3) void deform_all(const unsigned short* __restrict__ xt,
                                                     const unsigned short* __restrict__ wTb,
                                                     const unsigned short* __restrict__ owTb,
                                                     const float* __restrict__ bias,
                                                     const float* __restrict__ ob,
                                                     float* __restrict__ out) {
    __shared__ unsigned short SH[2 * 2 * 32 * 64];   // 16 KB: halo (13 KB) / S pairs
    __shared__ float offs[32 * 20];                  // [px][18 j + pad]

    int bid   = blockIdx.x;                 // 2304 = 8 images x 288 tiles
    int t     = threadIdx.x;
    int b     = bid & 7;                    // image per XCD
    int pbase = (bid >> 3) * 32;            // row-aligned 32-px tile
    int r0    = pbase / WW;                 // whole tile shares this row
    int c0    = pbase - r0 * WW;            // 0, 32, or 64

    // staging role: thread = (pixel, chunk)
    int e   = t & 7;
    int pxl = t >> 3;                       // 0..31
    int h   = r0, w = c0 + pxl;
    int sw  = pxl & 7;

    // MFMA roles
    int ln = t & 15;
    int qd = (t >> 4) & 3;
    int wv = t >> 6;

    const unsigned short* xb = xt + (size_t)b * HW * 64;

    // ================= phase A: halo load (3 rows x 34 cols, zero-padded) =====
#pragma unroll
    for (int p = 0; p < 4; ++p) {
        int rec = p * 32 + pxl;
        if (rec < 102) {
            int hr = rec / 34, hc = rec - hr * 34;
            int gr = r0 - 1 + hr, gc = c0 - 1 + hc;
            bool vd = (gr >= 0) & (gr < HH) & (gc >= 0) & (gc < WW);
            uint4 v = make_uint4(0u, 0u, 0u, 0u);
            if (vd) v = *(const uint4*)(xb + (size_t)(gr * WW + gc) * 64 + e * 8);
            *(uint4*)&SH[rec * 64 + ((e ^ (hc & 7)) << 3)] = v;
        }
    }
    __syncthreads();

    // ---- phase A MFMA: 9 taps straight from halo LDS, no more barriers ----
    int ptA = wv & 1, jtA = wv >> 1;
    f32x4 accj = {0.f, 0.f, 0.f, 0.f};
#pragma unroll
    for (int tap = 0; tap < 9; ++tap) {
        int r = tap / 3, s = tap - r * 3;
        int cH = ptA * 16 + ln + s;                  // halo column for this lane
        int ba = (r * 34 + cH) * 64;
        BF8 fa0, fa1, fb0, fb1;
        fa0.u = *(const uint4*)&SH[ba + ((qd       ^ (cH & 7)) << 3)];
        fa1.u = *(const uint4*)&SH[ba + (((qd + 4) ^ (cH & 7)) << 3)];
        const unsigned short* brow = owTb + (size_t)(jtA * 16 + ln) * 576 + tap * 64 + qd * 8;
        fb0.u = *(const uint4*)brow;
        fb1.u = *(const uint4*)(brow + 32);
        accj = __builtin_amdgcn_mfma_f32_16x16x32_bf16(fa0.v, fb0.v, accj, 0, 0, 0);
        accj = __builtin_amdgcn_mfma_f32_16x16x32_bf16(fa1.v, fb1.v, accj, 0, 0, 0);
    }
    {
        int j = jtA * 16 + ln;
        if (j < 18) {
            int   rowp = ptA * 16 + qd * 4;
            float obj  = ob[j];
#pragma unroll
            for (int rg = 0; rg < 4; ++rg) offs[(rowp + rg) * 20 + j] = accj[rg] + obj;
        }
    }
    __syncthreads();   // offs visible; all halo reads done before S overwrites SH

    float oy[9], ox[9];
#pragma unroll
    for (int k = 0; k < 9; ++k) {
        float2 p = *(const float2*)&offs[pxl * 20 + 2 * k];
        oy[k] = p.x; ox[k] = p.y;
    }

    // ================= phase B: 2 taps per barrier + cross-step prefetch ======
    f32x4 acc[2] = {{0.f,0.f,0.f,0.f},{0.f,0.f,0.f,0.f}};

    uint4 cc[2][4], cn[2][4];
    float gc[2][4], gn[2][4];

    auto issue = [&](int tap, uint4 (&C)[4], float (&G)[4]) {
        int r = tap / 3, s = tap - r * 3;
        int aa[4];
        bl_setup(h, w, r, s, oy[tap], ox[tap], aa, G);
#pragma unroll
        for (int c = 0; c < 4; ++c) C[c] = *(const uint4*)(xb + aa[c] + e * 8);
    };

    issue(0, cc[0], gc[0]);
    issue(1, cc[1], gc[1]);

#pragma unroll
    for (int step = 0; step < 5; ++step) {
        int  buf  = step & 1;
        int  t0   = 2 * step;
        bool has1 = (t0 + 1) < 9;

        // prefetch next pair (loads fly across combine + barrier + MFMA)
        if (t0 + 2 < 9) issue(t0 + 2, cn[0], gn[0]);
        if (t0 + 3 < 9) issue(t0 + 3, cn[1], gn[1]);

        // combine current pair -> S slots
#pragma unroll
        for (int tp = 0; tp < 2; ++tp) {
            if (tp == 0 || has1) {
                BF8 q0, q1, q2, q3;
                q0.u = cc[tp][0]; q1.u = cc[tp][1]; q2.u = cc[tp][2]; q3.u = cc[tp][3];
                float vv[8];
#pragma unroll
                for (int i = 0; i < 8; ++i)
                    vv[i] = gc[tp][0] * bf2f(q0.s[i]) + gc[tp][1] * bf2f(q1.s[i])
                          + gc[tp][2] * bf2f(q2.s[i]) + gc[tp][3] * bf2f(q3.s[i]);
                uint4 sv;
                sv.x = pkbf(vv[0], vv[1]); sv.y = pkbf(vv[2], vv[3]);
                sv.z = pkbf(vv[4], vv[5]); sv.w = pkbf(vv[6], vv[7]);
                *(uint4*)&SH[((buf * 2 + tp) * 32 + pxl) * 64 + ((e ^ sw) << 3)] = sv;
            }
        }
        __syncthreads();

        // MFMA both taps; B-frags direct from L1-hot wTb
#pragma unroll
        for (int tp = 0; tp < 2; ++tp) {
            if (tp == 0 || has1) {
                int tk = t0 + tp;
                const unsigned short* wb = wTb + (size_t)tk * 4096 + (wv * 16 + ln) * 64 + qd * 8;
                BF8 fb0, fb1;
                fb0.u = *(const uint4*)wb;
                fb1.u = *(const uint4*)(wb + 32);
#pragma unroll
                for (int pt = 0; pt < 2; ++pt) {
                    int row = pt * 16 + ln, rs2 = row & 7;
                    BF8 fa0, fa1;
                    fa0.u = *(const uint4*)&SH[((buf * 2 + tp) * 32 + row) * 64 + ((qd       ^ rs2) << 3)];
                    fa1.u = *(const uint4*)&SH[((buf * 2 + tp) * 32 + row) * 64 + (((qd + 4) ^ rs2) << 3)];
                    acc[pt] = __builtin_amdgcn_mfma_f32_16x16x32_bf16(fa0.v, fb0.v, acc[pt], 0, 0, 0);
                    acc[pt] = __builtin_amdgcn_mfma_f32_16x16x32_bf16(fa1.v, fb1.v, acc[pt], 0, 0, 0);
                }
            }
        }
        // rotate pipeline
#pragma unroll
        for (int tp = 0; tp < 2; ++tp)
#pragma unroll
            for (int c = 0; c < 4; ++c) { cc[tp][c] = cn[tp][c]; gc[tp][c] = gn[tp][c]; }
    }

    // ---- epilogue: D col=co, rows px = pt*16 + qd*4 + rg ----
    int   co = wv * 16 + ln;
    float bv = bias[co];
    float* ob2 = out + ((size_t)(b * 64 + co)) * HW + pbase + qd * 4;
#pragma unroll
    for (int pt = 0; pt < 2; ++pt) {
        float4 st;
        st.x = acc[pt].x + bv; st.y = acc[pt].y + bv;
        st.z = acc[pt].z + bv; st.w = acc[pt].w + bv;
        *(float4*)(ob2 + pt * 16) = st;
    }
}

// ---------------------------------------------------------------------------
extern "C" void kernel_launch(void* const* d_in, const int* in_sizes, int n_in,
                              void* d_out, int out_size, void* d_ws, size_t ws_size,
                              hipStream_t stream) {
    const float* x      = (const float*)d_in[0];   // 8*64*96*96
    const float* weight = (const float*)d_in[1];   // 64*64*3*3
    const float* bias   = (const float*)d_in[2];   // 64
    const float* off_w  = (const float*)d_in[3];   // 18*64*3*3
    const float* off_b  = (const float*)d_in[4];   // 18
    float* out = (float*)d_out;

    unsigned short* xt   = (unsigned short*)d_ws;  // 4,718,592 bf16
    unsigned short* wTb  = xt + 4718592;           // 36,864 bf16
    unsigned short* owTb = wTb + 36864;            // 18,432 bf16

    hipLaunchKernelGGL(xcvt_prep,  dim3(1152), dim3(256), 0, stream,
                       x, weight, off_w, xt, wTb, owTb);
    hipLaunchKernelGGL(deform_all, dim3(2304), dim3(256), 0, stream,
                       xt, wTb, owTb, bias, off_b, out);
}